// Round 6
// baseline (2844.202 us; speedup 1.0000x reference)
//
#include <hip/hip_runtime.h>
#include <cstdint>
#include <cstddef>

// ---------------------------------------------------------------------------
// EdgeDecoder, transposed formulation, L0 SPLIT BY SET (anti-spill v3):
//   H0^T = W0^T · X^T   (W0^T A-frags from LDS, gathered edges = B operand)
//   H1^T = W1^T · H0^T  (W1^T A-frags streamed from prepacked global/L1-L2)
//   p    = (W2 replicated-rows) · H1^T
// L0 runs once per 16-edge set with only one set's gather (32 regs) live;
// L1/W2 join the two sets so W1/W2 frags are read once per tile. Phase peaks
// ~92 / ~108 regs -> fits the 128 budget of launch_bounds(512,4) even under
// the allocator's 64/64 VGPR/AGPR split. Inter-layer C->B transform is a pure
// register re-pack (prepacked k-permutation on W1/W2).
// ---------------------------------------------------------------------------

#define E_EDGES   1000000
#define NTILES    31250          // E / 32
#define NUSER_H   12800000       // 100000*128 halfs
#define WB        19200000       // half index where prepacked weights start
// per-decoder prepacked layout (halfs):
#define W1_OFF    32768          // W1 frags (16384)
#define W2_OFF    49152          // W2 frags (2048)
#define B0F_OFF   51200          // b0 as f32 (256 halfs = 128 floats)
#define B1F_OFF   51456          // b1 as f32
#define DSTRIDE   51712
// LDS (halfs): w0f 0..32767 | w2f 32768 | b0f 34816 | b1f 35072
#define LDS_H     35328          // 70656 B -> 2 blocks/CU

typedef _Float16 half8  __attribute__((ext_vector_type(8)));
typedef _Float16 half2v __attribute__((ext_vector_type(2)));
typedef _Float16 half4v __attribute__((ext_vector_type(4)));
typedef float    f32x4  __attribute__((ext_vector_type(4)));

union HB { half2v h2[4]; half8 h8; };

__device__ __forceinline__ float elu(float x) {
    return x > 0.f ? x : (__expf(x) - 1.f);
}

__device__ __forceinline__ half2v pk(float a, float b) {
    return __builtin_bit_cast(half2v, __builtin_amdgcn_cvt_pkrtz(a, b));
}

// ---- prep: fp32 embeddings -> f16 tables ----------------------------------
__global__ void prep_emb(const float* __restrict__ user_emb,
                         const float* __restrict__ item_emb,
                         _Float16* __restrict__ ws) {
    int i = blockIdx.x * 256 + threadIdx.x;        // float4 index over 4.8M
    const float* src; _Float16* dst;
    if (i < 3200000) { src = user_emb; dst = ws; }
    else { i -= 3200000; src = item_emb; dst = ws + NUSER_H; }
    float4 f = ((const float4*)src)[i];
    half4v h;
    h[0] = (_Float16)f.x; h[1] = (_Float16)f.y;
    h[2] = (_Float16)f.z; h[3] = (_Float16)f.w;
    ((half4v*)dst)[i] = h;
}

// ---- prep: weights -> prepacked f16 fragment order ------------------------
__global__ void prep_w(const float* __restrict__ W0_ui, const float* __restrict__ W1_ui,
                       const float* __restrict__ W2_ui, const float* __restrict__ b0_ui,
                       const float* __restrict__ b1_ui,
                       const float* __restrict__ W0_iu, const float* __restrict__ W1_iu,
                       const float* __restrict__ W2_iu, const float* __restrict__ b0_iu,
                       const float* __restrict__ b1_iu,
                       _Float16* __restrict__ wdst) {
    const int wid = blockIdx.x * 4 + (threadIdx.x >> 6);
    const int l = threadIdx.x & 63;
    const int n = l & 15, g = l >> 4;
    if (wid < 128) {
        // W0^T A-frags: frag f=kk*8+j; lane: row c1 = j*16+n, k = kk*32+g*8+i
        const int dec = wid >> 6, f = wid & 63;
        const float* W0 = dec ? W0_iu : W0_ui;
        const int kk = f >> 3, j = f & 7;
        half8 fr;
        #pragma unroll
        for (int i = 0; i < 8; ++i)
            fr[i] = (_Float16)W0[(kk * 32 + g * 8 + i) * 128 + j * 16 + n];
        *(half8*)&wdst[dec * DSTRIDE + f * 512 + l * 8] = fr;
    } else if (wid < 192) {
        // W1^T A-frags with permuted k-order matching the register re-pack:
        // k-pos (kk2, quad g, i) <-> channel c1 = (2*kk2+(i>>2))*16 + g*4 + (i&3)
        const int q = wid - 128, dec = q >> 5, f = q & 31;
        const float* W1 = dec ? W1_iu : W1_ui;
        const int kk2 = f >> 3, j2 = f & 7;
        half8 fr;
        #pragma unroll
        for (int i = 0; i < 8; ++i) {
            const int c1 = (2 * kk2 + (i >> 2)) * 16 + g * 4 + (i & 3);
            fr[i] = (_Float16)W1[c1 * 128 + j2 * 16 + n];
        }
        *(half8*)&wdst[dec * DSTRIDE + W1_OFF + f * 512 + l * 8] = fr;
    } else if (wid < 200) {
        // W2 replicated-row A-frags, same permuted k-order over c2
        const int q = wid - 192, dec = q >> 2, kkf = q & 3;
        const float* W2 = dec ? W2_iu : W2_ui;
        half8 fr;
        #pragma unroll
        for (int i = 0; i < 8; ++i)
            fr[i] = (_Float16)W2[(2 * kkf + (i >> 2)) * 16 + g * 4 + (i & 3)];
        *(half8*)&wdst[dec * DSTRIDE + W2_OFF + kkf * 512 + l * 8] = fr;
    } else if (wid < 202) {
        // biases as f32
        const int dec = wid - 200;
        const float* b0 = dec ? b0_iu : b0_ui;
        const float* b1 = dec ? b1_iu : b1_ui;
        float* d0 = (float*)&wdst[dec * DSTRIDE + B0F_OFF];
        float* d1 = (float*)&wdst[dec * DSTRIDE + B1F_OFF];
        d0[2 * l]     = b0[2 * l];
        d0[2 * l + 1] = b0[2 * l + 1];
        d1[2 * l]     = b1[2 * l];
        d1[2 * l + 1] = b1[2 * l + 1];
    }
}

// ---- main ------------------------------------------------------------------
__global__ __launch_bounds__(512, 4) void edge_mlp(
    const _Float16* __restrict__ tab16,     // f16 tables base (user @0, item @NUSER_H)
    const _Float16* __restrict__ wpre,      // prepacked weights base
    const int* __restrict__ ui_src, const int* __restrict__ ui_dst,
    const int* __restrict__ iu_src, const int* __restrict__ iu_dst,
    const float* __restrict__ b2_ui, const float* __restrict__ b2_iu,
    float* __restrict__ out)
{
    __shared__ __align__(16) _Float16 lds[LDS_H];
    const int tid = threadIdx.x;
    const int l = tid & 63, w = tid >> 6;
    const int n = l & 15, g = l >> 4;
    const int dec = (int)(blockIdx.x >> 8);
    const int b8  = (int)(blockIdx.x & 255);

    const _Float16* stab = dec ? tab16 + NUSER_H : tab16;
    const _Float16* dtab = dec ? tab16 : tab16 + NUSER_H;
    const int* sidx = dec ? iu_src : ui_src;
    const int* didx = dec ? iu_dst : ui_dst;
    const _Float16* wreg = wpre + (size_t)dec * DSTRIDE;
    const float b2s = dec ? b2_iu[0] : b2_ui[0];
    float* op = out + dec * E_EDGES;

    // stage W0^T frags (64 KB) + W2 frags + f32 biases into LDS
    #pragma unroll
    for (int q = 0; q < 8; ++q) {
        const int f = w * 8 + q;
        *(half8*)&lds[f * 512 + l * 8] = *(const half8*)&wreg[f * 512 + l * 8];
    }
    if (tid < 320)
        *(half8*)&lds[32768 + tid * 8] = *(const half8*)&wreg[W2_OFF + tid * 8];
    __syncthreads();

    const half8* w0f = (const half8*)lds;               // frag f=kk*8+j: [f*64+l]
    const half8* w2f = (const half8*)&lds[32768];       // frag kkf: [kkf*64+l]
    const float* b0f = (const float*)&lds[34816];
    const float* b1f = (const float*)&lds[35072];
    const half8* w1f = (const half8*)&wreg[W1_OFF];     // frag f=kk2*8+j2: [f*64+l]

    const f32x4 z4 = (f32x4){0.f, 0.f, 0.f, 0.f};

    int t = b8 * 8 + w;                  // 2048 waves per decoder
    int si0 = sidx[t * 32 + n];
    int si1 = sidx[t * 32 + 16 + n];
    int di0 = didx[t * 32 + n];
    int di1 = didx[t * 32 + 16 + n];

    while (true) {
        const int e0 = t * 32;
        const _Float16* ps0 = stab + (((size_t)(unsigned)si0) << 7) + g * 8;
        const _Float16* ps1 = stab + (((size_t)(unsigned)si1) << 7) + g * 8;
        const _Float16* pd0 = dtab + (((size_t)(unsigned)di0) << 7) + g * 8;
        const _Float16* pd1 = dtab + (((size_t)(unsigned)di1) << 7) + g * 8;

        // ================= set 0: gather + layer 0 =================
        half8 a[8];
        #pragma unroll
        for (int kk = 0; kk < 4; ++kk) {
            a[kk]     = *(const half8*)(ps0 + kk * 32);
            a[4 + kk] = *(const half8*)(pd0 + kk * 32);
        }
        HB hb0[4];
        #pragma unroll
        for (int j = 0; j < 8; ++j) {
            f32x4 c = __builtin_amdgcn_mfma_f32_16x16x32_f16(w0f[j * 64 + l], a[0], z4, 0, 0, 0);
            #pragma unroll
            for (int kk = 1; kk < 8; ++kk)
                c = __builtin_amdgcn_mfma_f32_16x16x32_f16(w0f[(kk * 8 + j) * 64 + l], a[kk], c, 0, 0, 0);
            f32x4 bb = *(const f32x4*)&b0f[j * 16 + g * 4];
            hb0[j >> 1].h2[(j & 1) * 2]     = pk(elu(c[0] + bb[0]), elu(c[1] + bb[1]));
            hb0[j >> 1].h2[(j & 1) * 2 + 1] = pk(elu(c[2] + bb[2]), elu(c[3] + bb[3]));
        }

        // ================= set 1: gather + layer 0 =================
        #pragma unroll
        for (int kk = 0; kk < 4; ++kk) {
            a[kk]     = *(const half8*)(ps1 + kk * 32);
            a[4 + kk] = *(const half8*)(pd1 + kk * 32);
        }
        HB hb1[4];
        #pragma unroll
        for (int j = 0; j < 8; ++j) {
            f32x4 c = __builtin_amdgcn_mfma_f32_16x16x32_f16(w0f[j * 64 + l], a[0], z4, 0, 0, 0);
            #pragma unroll
            for (int kk = 1; kk < 8; ++kk)
                c = __builtin_amdgcn_mfma_f32_16x16x32_f16(w0f[(kk * 8 + j) * 64 + l], a[kk], c, 0, 0, 0);
            f32x4 bb = *(const f32x4*)&b0f[j * 16 + g * 4];
            hb1[j >> 1].h2[(j & 1) * 2]     = pk(elu(c[0] + bb[0]), elu(c[1] + bb[1]));
            hb1[j >> 1].h2[(j & 1) * 2 + 1] = pk(elu(c[2] + bb[2]), elu(c[3] + bb[3]));
        }

        // ---- next-tile index prefetch (a dead now) ----
        const int tn = t + 2048;
        const bool more = tn < NTILES;
        int nsi0 = 0, nsi1 = 0, ndi0 = 0, ndi1 = 0;
        if (more) {
            nsi0 = sidx[tn * 32 + n];
            nsi1 = sidx[tn * 32 + 16 + n];
            ndi0 = didx[tn * 32 + n];
            ndi1 = didx[tn * 32 + 16 + n];
        }

        // ========== layer 1, joint over both sets (W1 read once) ==========
        HB pb0[4], pb1[4];
        #pragma unroll
        for (int j2 = 0; j2 < 8; ++j2) {
            half8 wa0 = w1f[j2 * 64 + l];
            half8 wa1 = w1f[(8 + j2) * 64 + l];
            half8 wa2 = w1f[(16 + j2) * 64 + l];
            half8 wa3 = w1f[(24 + j2) * 64 + l];
            f32x4 c0 = __builtin_amdgcn_mfma_f32_16x16x32_f16(wa0, hb0[0].h8, z4, 0, 0, 0);
            f32x4 c1 = __builtin_amdgcn_mfma_f32_16x16x32_f16(wa0, hb1[0].h8, z4, 0, 0, 0);
            c0 = __builtin_amdgcn_mfma_f32_16x16x32_f16(wa1, hb0[1].h8, c0, 0, 0, 0);
            c1 = __builtin_amdgcn_mfma_f32_16x16x32_f16(wa1, hb1[1].h8, c1, 0, 0, 0);
            c0 = __builtin_amdgcn_mfma_f32_16x16x32_f16(wa2, hb0[2].h8, c0, 0, 0, 0);
            c1 = __builtin_amdgcn_mfma_f32_16x16x32_f16(wa2, hb1[2].h8, c1, 0, 0, 0);
            c0 = __builtin_amdgcn_mfma_f32_16x16x32_f16(wa3, hb0[3].h8, c0, 0, 0, 0);
            c1 = __builtin_amdgcn_mfma_f32_16x16x32_f16(wa3, hb1[3].h8, c1, 0, 0, 0);
            f32x4 bb = *(const f32x4*)&b1f[j2 * 16 + g * 4];
            const int kk2 = j2 >> 1, p = (j2 & 1) * 2;
            pb0[kk2].h2[p]     = pk(elu(c0[0] + bb[0]), elu(c0[1] + bb[1]));
            pb0[kk2].h2[p + 1] = pk(elu(c0[2] + bb[2]), elu(c0[3] + bb[3]));
            pb1[kk2].h2[p]     = pk(elu(c1[0] + bb[0]), elu(c1[1] + bb[1]));
            pb1[kk2].h2[p + 1] = pk(elu(c1[2] + bb[2]), elu(c1[3] + bb[3]));
        }

        // ---- final layer via MFMA with replicated-row W2: all D rows = p ----
        f32x4 d0 = __builtin_amdgcn_mfma_f32_16x16x32_f16(w2f[l], pb0[0].h8, z4, 0, 0, 0);
        f32x4 d1 = __builtin_amdgcn_mfma_f32_16x16x32_f16(w2f[l], pb1[0].h8, z4, 0, 0, 0);
        #pragma unroll
        for (int kkf = 1; kkf < 4; ++kkf) {
            half8 wf = w2f[kkf * 64 + l];
            d0 = __builtin_amdgcn_mfma_f32_16x16x32_f16(wf, pb0[kkf].h8, d0, 0, 0, 0);
            d1 = __builtin_amdgcn_mfma_f32_16x16x32_f16(wf, pb1[kkf].h8, d1, 0, 0, 0);
        }

        // ---- sigmoid + store: quads 0/1 store sets 0/1 (32 lanes, 128 B) ----
        const float pv = (g & 1) ? d1[0] : d0[0];
        const float r = 1.f / (1.f + __expf(-(pv + b2s)));
        if (g < 2) op[e0 + g * 16 + n] = r;

        if (!more) break;
        t = tn;
        si0 = nsi0; si1 = nsi1; di0 = ndi0; di1 = ndi1;
    }
}

extern "C" void kernel_launch(void* const* d_in, const int* in_sizes, int n_in,
                              void* d_out, int out_size, void* d_ws, size_t ws_size,
                              hipStream_t stream) {
    const float* user_emb = (const float*)d_in[0];
    const float* item_emb = (const float*)d_in[1];
    const int* ui_src = (const int*)d_in[2];
    const int* ui_dst = (const int*)d_in[3];
    const int* iu_src = (const int*)d_in[4];
    const int* iu_dst = (const int*)d_in[5];
    const float* W0_ui = (const float*)d_in[6];
    const float* b0_ui = (const float*)d_in[7];
    const float* W1_ui = (const float*)d_in[8];
    const float* b1_ui = (const float*)d_in[9];
    const float* W2_ui = (const float*)d_in[10];
    const float* b2_ui = (const float*)d_in[11];
    const float* W0_iu = (const float*)d_in[12];
    const float* b0_iu = (const float*)d_in[13];
    const float* W1_iu = (const float*)d_in[14];
    const float* b1_iu = (const float*)d_in[15];
    const float* W2_iu = (const float*)d_in[16];
    const float* b2_iu = (const float*)d_in[17];
    float* out = (float*)d_out;

    _Float16* ws = (_Float16*)d_ws;
    prep_emb<<<dim3(18750), dim3(256), 0, stream>>>(user_emb, item_emb, ws);
    prep_w<<<dim3(51), dim3(256), 0, stream>>>(W0_ui, W1_ui, W2_ui, b0_ui, b1_ui,
                                               W0_iu, W1_iu, W2_iu, b0_iu, b1_iu,
                                               ws + WB);
    edge_mlp<<<dim3(512), dim3(512), 0, stream>>>(
        ws, ws + WB, ui_src, ui_dst, iu_src, iu_dst, b2_ui, b2_iu, out);
}